// Round 2
// baseline (1047.353 us; speedup 1.0000x reference)
//
#include <hip/hip_runtime.h>
#include <cstdint>

#define IN_DIM 128
#define HC 256          // H*C
#define NEG_SLOPE 0.2f
#define BN_EPS 1e-5f

// ---------------- GEMM: x_l = F@W_l + b_l ; x_r = F@W_r + b_r ----------------
// tile: BM=64 rows, BN=128 cols, K chunked by 32. grid.y: 0,1 -> x_l ; 2,3 -> x_r
#define BM 64
#define BNC 128
#define KK 32

__global__ __launch_bounds__(256) void gemm_xlxr(
    const float* __restrict__ F,
    const float* __restrict__ Wl, const float* __restrict__ bl,
    const float* __restrict__ Wr, const float* __restrict__ br,
    float* __restrict__ xl, float* __restrict__ xr, int n)
{
    __shared__ float As[BM][KK];    // 8 KB
    __shared__ float Bs[KK][BNC];   // 16 KB
    const int nt = blockIdx.y;
    const float* W = (nt < 2) ? Wl : Wr;
    const float* bb = (nt < 2) ? bl : br;
    float* X = (nt < 2) ? xl : xr;
    const int col0 = (nt & 1) * BNC;
    const int row0 = blockIdx.x * BM;
    const int t = threadIdx.x;
    const int tr = t >> 5;    // 0..7
    const int tc = t & 31;    // 0..31

    float acc[8][4];
#pragma unroll
    for (int r = 0; r < 8; ++r) { acc[r][0]=0.f; acc[r][1]=0.f; acc[r][2]=0.f; acc[r][3]=0.f; }

    for (int k0 = 0; k0 < IN_DIM; k0 += KK) {
#pragma unroll
        for (int i = 0; i < 8; ++i) {           // A tile 64x32
            int e = t + i * 256;
            int r = e >> 5, k = e & 31;
            int gr = row0 + r;
            As[r][k] = (gr < n) ? F[(size_t)gr * IN_DIM + k0 + k] : 0.f;
        }
#pragma unroll
        for (int i = 0; i < 16; ++i) {          // B tile 32x128
            int e = t + i * 256;
            int k = e >> 7, c = e & 127;
            Bs[k][c] = W[(size_t)(k0 + k) * HC + col0 + c];
        }
        __syncthreads();
#pragma unroll
        for (int k = 0; k < KK; ++k) {
            float4 b4 = *(const float4*)&Bs[k][tc * 4];
#pragma unroll
            for (int r = 0; r < 8; ++r) {
                float a = As[tr * 8 + r][k];
                acc[r][0] += a * b4.x; acc[r][1] += a * b4.y;
                acc[r][2] += a * b4.z; acc[r][3] += a * b4.w;
            }
        }
        __syncthreads();
    }
    float4 badd = *(const float4*)&bb[col0 + tc * 4];
#pragma unroll
    for (int r = 0; r < 8; ++r) {
        int gr = row0 + tr * 8 + r;
        if (gr < n) {
            float4 o;
            o.x = acc[r][0] + badd.x; o.y = acc[r][1] + badd.y;
            o.z = acc[r][2] + badd.z; o.w = acc[r][3] + badd.w;
            *(float4*)&X[(size_t)gr * HC + col0 + tc * 4] = o;
        }
    }
}

// ---------------- CSR build (edge_index is int32: ei[0..E-1]=src, ei[E..2E-1]=dst) ----
__global__ void hist_kernel(const int* __restrict__ ei, int* __restrict__ cnt,
                            int E, int n)
{
    int total = E + n;
    for (int e = blockIdx.x * blockDim.x + threadIdx.x; e < total;
         e += gridDim.x * blockDim.x) {
        int dst = (e < E) ? ei[(size_t)E + e] : (e - E);
        atomicAdd(&cnt[dst], 1);
    }
}

__global__ __launch_bounds__(1024) void scan_kernel(const int* __restrict__ cnt,
                                                    int* __restrict__ off,
                                                    int* __restrict__ cur, int n)
{
    __shared__ int sums[1024];
    int t = threadIdx.x;
    int chunk = (n + 1023) >> 10;
    int beg = t * chunk;
    int end = min(beg + chunk, n);
    int s = 0;
    for (int i = beg; i < end; ++i) s += cnt[i];
    sums[t] = s;
    __syncthreads();
    for (int d = 1; d < 1024; d <<= 1) {
        int v = (t >= d) ? sums[t - d] : 0;
        __syncthreads();
        sums[t] += v;
        __syncthreads();
    }
    int run = (t == 0) ? 0 : sums[t - 1];
    for (int i = beg; i < end; ++i) {
        off[i] = run; cur[i] = run;
        run += cnt[i];
    }
    if (t == 1023) off[n] = run;
}

__global__ void fill_kernel(const int* __restrict__ ei, int* __restrict__ cur,
                            int* __restrict__ csr_src, int E, int n)
{
    int total = E + n;
    for (int e = blockIdx.x * blockDim.x + threadIdx.x; e < total;
         e += gridDim.x * blockDim.x) {
        int src, dst;
        if (e < E) { src = ei[e]; dst = ei[(size_t)E + e]; }
        else       { src = dst = e - E; }
        int pos = atomicAdd(&cur[dst], 1);
        csr_src[pos] = src;
    }
}

// ---------------- per-node wave aggregation (online softmax) ----------------
__global__ __launch_bounds__(256) void gat_agg(
    const float* __restrict__ xl, const float* __restrict__ xr,
    const int* __restrict__ csr_src, const int* __restrict__ off,
    const float* __restrict__ att, const float* __restrict__ bias,
    float* __restrict__ out, int n)
{
    int wid = (blockIdx.x * blockDim.x + threadIdx.x) >> 6;   // one wave per node
    int lane = threadIdx.x & 63;
    if (wid >= n) return;
    int d = wid;

    float4 xr4 = *(const float4*)(xr + (size_t)d * HC + 4 * lane);
    float4 att4 = *(const float4*)(att + 4 * lane);

    int beg = off[d], end = off[d + 1];
    float m = -INFINITY;
    float lsum = 0.f;
    float4 acc = make_float4(0.f, 0.f, 0.f, 0.f);

    for (int i = beg; i < end; ++i) {
        int s = csr_src[i];
        float4 xl4 = *(const float4*)(xl + (size_t)s * HC + 4 * lane);
        float z0 = xl4.x + xr4.x, z1 = xl4.y + xr4.y;
        float z2 = xl4.z + xr4.z, z3 = xl4.w + xr4.w;
        float l0 = (z0 > 0.f) ? z0 : NEG_SLOPE * z0;
        float l1 = (z1 > 0.f) ? z1 : NEG_SLOPE * z1;
        float l2 = (z2 > 0.f) ? z2 : NEG_SLOPE * z2;
        float l3 = (z3 > 0.f) ? z3 : NEG_SLOPE * z3;
        float part = att4.x * l0 + att4.y * l1 + att4.z * l2 + att4.w * l3;
        // reduce across the 16 lanes of this head
        part += __shfl_xor(part, 1);
        part += __shfl_xor(part, 2);
        part += __shfl_xor(part, 4);
        part += __shfl_xor(part, 8);
        float alpha = part;
        if (alpha > m) {
            float scale = __expf(m - alpha);   // exp(-inf)=0 on first edge
            acc.x *= scale; acc.y *= scale; acc.z *= scale; acc.w *= scale;
            lsum *= scale;
            m = alpha;
        }
        float p = __expf(alpha - m);
        acc.x += p * xl4.x; acc.y += p * xl4.y;
        acc.z += p * xl4.z; acc.w += p * xl4.w;
        lsum += p;
    }
    float inv = 1.f / (lsum + 1e-16f);
    float4 b4 = *(const float4*)(bias + 4 * lane);
    float4 o;
    o.x = acc.x * inv + b4.x; o.y = acc.y * inv + b4.y;
    o.z = acc.z * inv + b4.z; o.w = acc.w * inv + b4.w;
    *(float4*)(out + (size_t)d * HC + 4 * lane) = o;
}

// ---------------- BatchNorm ----------------
#define NB_BN 512
__global__ __launch_bounds__(256) void bn_partial(const float* __restrict__ out,
                                                  float* __restrict__ partials, int n)
{
    int c = threadIdx.x;            // channel
    int b = blockIdx.x;
    int chunk = (n + NB_BN - 1) / NB_BN;
    int beg = b * chunk;
    int end = min(beg + chunk, n);
    float s = 0.f, s2 = 0.f;
    for (int r = beg; r < end; ++r) {
        float v = out[(size_t)r * HC + c];
        s += v; s2 += v * v;
    }
    partials[(size_t)b * 512 + c] = s;
    partials[(size_t)b * 512 + 256 + c] = s2;
}

__global__ __launch_bounds__(256) void bn_final(const float* __restrict__ partials,
                                                float* __restrict__ stats, int n)
{
    int c = threadIdx.x;
    float s = 0.f, s2 = 0.f;
    for (int b = 0; b < NB_BN; ++b) {
        s += partials[(size_t)b * 512 + c];
        s2 += partials[(size_t)b * 512 + 256 + c];
    }
    float mean = s / (float)n;
    float var = s2 / (float)n - mean * mean;
    stats[c] = mean;
    stats[256 + c] = rsqrtf(var + BN_EPS);
}

__global__ void bn_apply(float* __restrict__ out, const float* __restrict__ stats,
                         const float* __restrict__ gamma, const float* __restrict__ beta,
                         long long total4)
{
    long long stride = (long long)gridDim.x * blockDim.x;
    for (long long i = blockIdx.x * (long long)blockDim.x + threadIdx.x; i < total4;
         i += stride) {
        int cb = ((int)(i & 63)) * 4;     // channel of first component
        float4 v = ((const float4*)out)[i];
        float4 o;
        o.x = fmaxf(0.f, (v.x - stats[cb + 0]) * stats[256 + cb + 0] * gamma[cb + 0] + beta[cb + 0]);
        o.y = fmaxf(0.f, (v.y - stats[cb + 1]) * stats[256 + cb + 1] * gamma[cb + 1] + beta[cb + 1]);
        o.z = fmaxf(0.f, (v.z - stats[cb + 2]) * stats[256 + cb + 2] * gamma[cb + 2] + beta[cb + 2]);
        o.w = fmaxf(0.f, (v.w - stats[cb + 3]) * stats[256 + cb + 3] * gamma[cb + 3] + beta[cb + 3]);
        ((float4*)out)[i] = o;
    }
}

// ---------------- launch ----------------
extern "C" void kernel_launch(void* const* d_in, const int* in_sizes, int n_in,
                              void* d_out, int out_size, void* d_ws, size_t ws_size,
                              hipStream_t stream)
{
    const float* feature = (const float*)d_in[0];
    const int* ei        = (const int*)d_in[1];      // int32! src=ei[0..E), dst=ei[E..2E)
    const float* Wl   = (const float*)d_in[2];
    const float* bl   = (const float*)d_in[3];
    const float* Wr   = (const float*)d_in[4];
    const float* br   = (const float*)d_in[5];
    const float* att  = (const float*)d_in[6];
    const float* bias = (const float*)d_in[7];
    const float* gamma = (const float*)d_in[8];
    const float* beta  = (const float*)d_in[9];

    const int n = in_sizes[0] / IN_DIM;
    const int E = in_sizes[1] / 2;
    const int Etot = E + n;

    // workspace carve (16B aligned)
    char* ws = (char*)d_ws;
    size_t o = 0;
    auto carve = [&](size_t bytes) -> void* {
        void* p = ws + o; o = (o + bytes + 15) & ~(size_t)15; return p;
    };
    float* xl      = (float*)carve((size_t)n * HC * sizeof(float));
    float* xr      = (float*)carve((size_t)n * HC * sizeof(float));
    int*   csr_src = (int*)carve((size_t)Etot * sizeof(int));
    int*   cnt     = (int*)carve((size_t)n * sizeof(int));
    int*   off     = (int*)carve((size_t)(n + 1) * sizeof(int));
    int*   cur     = (int*)carve((size_t)n * sizeof(int));
    float* partials = (float*)carve((size_t)NB_BN * 512 * sizeof(float));
    float* stats   = (float*)carve(512 * sizeof(float));
    float* outf = (float*)d_out;

    if (o > ws_size) return;   // ws too small: fail cleanly (zeros), don't fault

    // 1. projections
    dim3 ggrid((n + BM - 1) / BM, 4);
    gemm_xlxr<<<ggrid, 256, 0, stream>>>(feature, Wl, bl, Wr, br, xl, xr, n);

    // 2. CSR by dst
    hipMemsetAsync(cnt, 0, (size_t)n * sizeof(int), stream);
    hist_kernel<<<4096, 256, 0, stream>>>(ei, cnt, E, n);
    scan_kernel<<<1, 1024, 0, stream>>>(cnt, off, cur, n);
    fill_kernel<<<4096, 256, 0, stream>>>(ei, cur, csr_src, E, n);

    // 3. per-node online-softmax aggregation (one wave per node)
    int agg_blocks = (n + 3) / 4;   // 256 threads = 4 waves = 4 nodes
    gat_agg<<<agg_blocks, 256, 0, stream>>>(xl, xr, csr_src, off, att, bias, outf, n);

    // 4. BatchNorm + ReLU
    bn_partial<<<NB_BN, 256, 0, stream>>>(outf, partials, n);
    bn_final<<<1, 256, 0, stream>>>(partials, stats, n);
    long long total4 = (long long)n * (HC / 4);
    bn_apply<<<2048, 256, 0, stream>>>(outf, stats, gamma, beta, total4);
}

// Round 3
// 771.590 us; speedup vs baseline: 1.3574x; 1.3574x over previous
//
#include <hip/hip_runtime.h>
#include <cstdint>

#define IN_DIM 128
#define HC 256          // H*C
#define NEG_SLOPE 0.2f
#define BN_EPS 1e-5f

typedef short bf16x8 __attribute__((ext_vector_type(8)));   // 8 bf16 = 4 VGPR
typedef float f32x4 __attribute__((ext_vector_type(4)));

__device__ __forceinline__ unsigned short f2bf(float f) {
    union { float f; unsigned int u; } v; v.f = f;
    unsigned int r = (v.u + 0x7FFFu + ((v.u >> 16) & 1u)) >> 16;   // RNE
    return (unsigned short)r;
}
__device__ __forceinline__ float bf2f(unsigned short h) {
    union { unsigned int u; float f; } v; v.u = ((unsigned int)h) << 16;
    return v.f;
}

// ---------- cast W -> fragment layout: Wfrag[((j*4+kk)*64+l)*8+m] = Wcat[k][col] ----------
// j=0..31 over 512 cols (cols 0..255 = Wl, 256..511 = Wr); k = kk*32 + (l>>4)*8 + m
__global__ __launch_bounds__(64) void cast_w(
    const float* __restrict__ Wl, const float* __restrict__ Wr,
    unsigned short* __restrict__ Wfrag)
{
    int j = blockIdx.x >> 2;          // 0..31
    int kk = blockIdx.x & 3;          // 0..3
    int l = threadIdx.x;              // 0..63
    int col = j * 16 + (l & 15);      // 0..511
    const float* W = (col < 256) ? Wl : Wr;
    int c = col & 255;
    unsigned short tmp[8];
#pragma unroll
    for (int m = 0; m < 8; ++m) {
        int k = kk * 32 + ((l >> 4) << 3) + m;
        tmp[m] = f2bf(W[(size_t)k * 256 + c]);
    }
    ulonglong2* dst = (ulonglong2*)(Wfrag + ((size_t)(j * 4 + kk) * 64 + l) * 8);
    *dst = *(ulonglong2*)tmp;
}

// ---------- cast A -> fragment layout: Afrag[((i*4+kk)*64+l)*8+m] = A[i*16+(l&15)][kk*32+(l>>4)*8+m]
__global__ __launch_bounds__(256) void cast_a(
    const float* __restrict__ A, unsigned short* __restrict__ Afrag, int n)
{
    int i = blockIdx.x;               // row tile
    int kk = threadIdx.x >> 6;        // wave id = k-chunk
    int l = threadIdx.x & 63;
    int row = i * 16 + (l & 15);
    int k0 = kk * 32 + ((l >> 4) << 3);
    float4 f0 = make_float4(0.f, 0.f, 0.f, 0.f), f1 = f0;
    if (row < n) {
        const float* p = A + (size_t)row * IN_DIM + k0;
        f0 = *(const float4*)p;
        f1 = *(const float4*)(p + 4);
    }
    unsigned short tmp[8];
    tmp[0] = f2bf(f0.x); tmp[1] = f2bf(f0.y); tmp[2] = f2bf(f0.z); tmp[3] = f2bf(f0.w);
    tmp[4] = f2bf(f1.x); tmp[5] = f2bf(f1.y); tmp[6] = f2bf(f1.z); tmp[7] = f2bf(f1.w);
    ulonglong2* dst = (ulonglong2*)(Afrag + ((size_t)(i * 4 + kk) * 64 + l) * 8);
    *dst = *(ulonglong2*)tmp;
}

// ---------- MFMA GEMM: xl/xr (bf16, row-major [n][256]) = A @ [Wl|Wr] + bias ----------
__global__ __launch_bounds__(256) void gemm_mfma(
    const unsigned short* __restrict__ Afrag, const unsigned short* __restrict__ Wfrag,
    const float* __restrict__ bl, const float* __restrict__ br,
    unsigned short* __restrict__ xl, unsigned short* __restrict__ xr,
    int n, int ntiles)
{
    int i = blockIdx.x * 4 + (threadIdx.x >> 6);   // row tile
    if (i >= ntiles) return;
    int l = threadIdx.x & 63;

    const bf16x8* av = (const bf16x8*)(Afrag + ((size_t)i * 4 * 64 + l) * 8);
    bf16x8 a0 = av[0 * 64], a1 = av[1 * 64], a2 = av[2 * 64], a3 = av[3 * 64];

    const bf16x8* wv = (const bf16x8*)Wfrag + l;
    int cl = l & 15;
    int rbase = i * 16 + ((l >> 4) << 2);

#pragma unroll 4
    for (int j = 0; j < 32; ++j) {
        const bf16x8* bp = wv + (size_t)j * 4 * 64;
        f32x4 acc = {0.f, 0.f, 0.f, 0.f};
        acc = __builtin_amdgcn_mfma_f32_16x16x32_bf16(a0, bp[0 * 64], acc, 0, 0, 0);
        acc = __builtin_amdgcn_mfma_f32_16x16x32_bf16(a1, bp[1 * 64], acc, 0, 0, 0);
        acc = __builtin_amdgcn_mfma_f32_16x16x32_bf16(a2, bp[2 * 64], acc, 0, 0, 0);
        acc = __builtin_amdgcn_mfma_f32_16x16x32_bf16(a3, bp[3 * 64], acc, 0, 0, 0);

        int col = j * 16 + cl;                 // 0..511
        unsigned short* X = (col < 256) ? xl : xr;
        int c = col & 255;
        float b = (col < 256) ? bl[c] : br[c];
#pragma unroll
        for (int q = 0; q < 4; ++q) {
            int row = rbase + q;
            if (row < n) X[(size_t)row * HC + c] = f2bf(acc[q] + b);
        }
    }
}

// ---------------- CSR build (edge_index int32: ei[0..E)=src, ei[E..2E)=dst) ----------
__global__ void hist_kernel(const int* __restrict__ ei, int* __restrict__ cnt,
                            int E, int n)
{
    int total = E + n;
    for (int e = blockIdx.x * blockDim.x + threadIdx.x; e < total;
         e += gridDim.x * blockDim.x) {
        int dst = (e < E) ? ei[(size_t)E + e] : (e - E);
        atomicAdd(&cnt[dst], 1);
    }
}

__global__ __launch_bounds__(1024) void scan_kernel(const int* __restrict__ cnt,
                                                    int* __restrict__ off,
                                                    int* __restrict__ cur, int n)
{
    __shared__ int sums[1024];
    int t = threadIdx.x;
    int chunk = (n + 1023) >> 10;
    int beg = t * chunk;
    int end = min(beg + chunk, n);
    int s = 0;
    for (int i = beg; i < end; ++i) s += cnt[i];
    sums[t] = s;
    __syncthreads();
    for (int d = 1; d < 1024; d <<= 1) {
        int v = (t >= d) ? sums[t - d] : 0;
        __syncthreads();
        sums[t] += v;
        __syncthreads();
    }
    int run = (t == 0) ? 0 : sums[t - 1];
    for (int i = beg; i < end; ++i) {
        off[i] = run; cur[i] = run;
        run += cnt[i];
    }
    if (t == 1023) off[n] = run;
}

__global__ void fill_kernel(const int* __restrict__ ei, int* __restrict__ cur,
                            int* __restrict__ csr_src, int E, int n)
{
    int total = E + n;
    for (int e = blockIdx.x * blockDim.x + threadIdx.x; e < total;
         e += gridDim.x * blockDim.x) {
        int src, dst;
        if (e < E) { src = ei[e]; dst = ei[(size_t)E + e]; }
        else       { src = dst = e - E; }
        int pos = atomicAdd(&cur[dst], 1);
        csr_src[pos] = src;
    }
}

// ---------------- per-node wave aggregation (online softmax, bf16 xl/xr) -----------
__global__ __launch_bounds__(256) void gat_agg(
    const unsigned short* __restrict__ xl, const unsigned short* __restrict__ xr,
    const int* __restrict__ csr_src, const int* __restrict__ off,
    const float* __restrict__ att, const float* __restrict__ bias,
    float* __restrict__ out, int n)
{
    int d = (blockIdx.x * blockDim.x + threadIdx.x) >> 6;   // one wave per node
    int lane = threadIdx.x & 63;
    if (d >= n) return;

    const ushort4* xlv = (const ushort4*)xl;
    ushort4 xru = ((const ushort4*)xr)[(size_t)d * 64 + lane];
    float xr0 = bf2f(xru.x), xr1 = bf2f(xru.y), xr2 = bf2f(xru.z), xr3 = bf2f(xru.w);
    float4 att4 = *(const float4*)(att + 4 * lane);

    int beg = off[d], end = off[d + 1];
    float m = -INFINITY;
    float lsum = 0.f;
    float ax = 0.f, ay = 0.f, az = 0.f, aw = 0.f;

    int i = beg;
    for (; i + 1 < end; i += 2) {
        int s0 = csr_src[i];
        int s1 = csr_src[i + 1];
        ushort4 u0 = xlv[(size_t)s0 * 64 + lane];
        ushort4 u1 = xlv[(size_t)s1 * 64 + lane];
        float f0x = bf2f(u0.x), f0y = bf2f(u0.y), f0z = bf2f(u0.z), f0w = bf2f(u0.w);
        float f1x = bf2f(u1.x), f1y = bf2f(u1.y), f1z = bf2f(u1.z), f1w = bf2f(u1.w);

        float z, p0, p1;
        z = f0x + xr0; p0  = att4.x * ((z > 0.f) ? z : NEG_SLOPE * z);
        z = f0y + xr1; p0 += att4.y * ((z > 0.f) ? z : NEG_SLOPE * z);
        z = f0z + xr2; p0 += att4.z * ((z > 0.f) ? z : NEG_SLOPE * z);
        z = f0w + xr3; p0 += att4.w * ((z > 0.f) ? z : NEG_SLOPE * z);
        z = f1x + xr0; p1  = att4.x * ((z > 0.f) ? z : NEG_SLOPE * z);
        z = f1y + xr1; p1 += att4.y * ((z > 0.f) ? z : NEG_SLOPE * z);
        z = f1z + xr2; p1 += att4.z * ((z > 0.f) ? z : NEG_SLOPE * z);
        z = f1w + xr3; p1 += att4.w * ((z > 0.f) ? z : NEG_SLOPE * z);

        // two interleaved 16-lane reductions (per-head)
        p0 += __shfl_xor(p0, 1);  p1 += __shfl_xor(p1, 1);
        p0 += __shfl_xor(p0, 2);  p1 += __shfl_xor(p1, 2);
        p0 += __shfl_xor(p0, 4);  p1 += __shfl_xor(p1, 4);
        p0 += __shfl_xor(p0, 8);  p1 += __shfl_xor(p1, 8);

        float mx = fmaxf(p0, p1);
        if (mx > m) {
            float sc = __expf(m - mx);     // exp(-inf)=0 on first pair
            ax *= sc; ay *= sc; az *= sc; aw *= sc; lsum *= sc;
            m = mx;
        }
        float e0 = __expf(p0 - m);
        float e1 = __expf(p1 - m);
        ax += e0 * f0x + e1 * f1x;
        ay += e0 * f0y + e1 * f1y;
        az += e0 * f0z + e1 * f1z;
        aw += e0 * f0w + e1 * f1w;
        lsum += e0 + e1;
    }
    if (i < end) {
        int s0 = csr_src[i];
        ushort4 u0 = xlv[(size_t)s0 * 64 + lane];
        float f0x = bf2f(u0.x), f0y = bf2f(u0.y), f0z = bf2f(u0.z), f0w = bf2f(u0.w);
        float z, p0;
        z = f0x + xr0; p0  = att4.x * ((z > 0.f) ? z : NEG_SLOPE * z);
        z = f0y + xr1; p0 += att4.y * ((z > 0.f) ? z : NEG_SLOPE * z);
        z = f0z + xr2; p0 += att4.z * ((z > 0.f) ? z : NEG_SLOPE * z);
        z = f0w + xr3; p0 += att4.w * ((z > 0.f) ? z : NEG_SLOPE * z);
        p0 += __shfl_xor(p0, 1);
        p0 += __shfl_xor(p0, 2);
        p0 += __shfl_xor(p0, 4);
        p0 += __shfl_xor(p0, 8);
        if (p0 > m) {
            float sc = __expf(m - p0);
            ax *= sc; ay *= sc; az *= sc; aw *= sc; lsum *= sc;
            m = p0;
        }
        float e0 = __expf(p0 - m);
        ax += e0 * f0x; ay += e0 * f0y; az += e0 * f0z; aw += e0 * f0w;
        lsum += e0;
    }

    float inv = 1.f / (lsum + 1e-16f);
    float4 b4 = *(const float4*)(bias + 4 * lane);
    float4 o;
    o.x = ax * inv + b4.x; o.y = ay * inv + b4.y;
    o.z = az * inv + b4.z; o.w = aw * inv + b4.w;
    *(float4*)(out + (size_t)d * HC + 4 * lane) = o;
}

// ---------------- BatchNorm ----------------
#define NB_BN 512
__global__ __launch_bounds__(256) void bn_partial(const float* __restrict__ out,
                                                  float* __restrict__ partials, int n)
{
    int c = threadIdx.x;
    int b = blockIdx.x;
    int chunk = (n + NB_BN - 1) / NB_BN;
    int beg = b * chunk;
    int end = min(beg + chunk, n);
    float s = 0.f, s2 = 0.f;
    for (int r = beg; r < end; ++r) {
        float v = out[(size_t)r * HC + c];
        s += v; s2 += v * v;
    }
    partials[(size_t)b * 512 + c] = s;
    partials[(size_t)b * 512 + 256 + c] = s2;
}

__global__ __launch_bounds__(256) void bn_final(const float* __restrict__ partials,
                                                float* __restrict__ stats, int n)
{
    int c = threadIdx.x;
    float s = 0.f, s2 = 0.f;
    for (int b = 0; b < NB_BN; ++b) {
        s += partials[(size_t)b * 512 + c];
        s2 += partials[(size_t)b * 512 + 256 + c];
    }
    float mean = s / (float)n;
    float var = s2 / (float)n - mean * mean;
    stats[c] = mean;
    stats[256 + c] = rsqrtf(var + BN_EPS);
}

__global__ void bn_apply(float* __restrict__ out, const float* __restrict__ stats,
                         const float* __restrict__ gamma, const float* __restrict__ beta,
                         long long total4)
{
    long long stride = (long long)gridDim.x * blockDim.x;
    for (long long i = blockIdx.x * (long long)blockDim.x + threadIdx.x; i < total4;
         i += stride) {
        int cb = ((int)(i & 63)) * 4;
        float4 v = ((const float4*)out)[i];
        float4 o;
        o.x = fmaxf(0.f, (v.x - stats[cb + 0]) * stats[256 + cb + 0] * gamma[cb + 0] + beta[cb + 0]);
        o.y = fmaxf(0.f, (v.y - stats[cb + 1]) * stats[256 + cb + 1] * gamma[cb + 1] + beta[cb + 1]);
        o.z = fmaxf(0.f, (v.z - stats[cb + 2]) * stats[256 + cb + 2] * gamma[cb + 2] + beta[cb + 2]);
        o.w = fmaxf(0.f, (v.w - stats[cb + 3]) * stats[256 + cb + 3] * gamma[cb + 3] + beta[cb + 3]);
        ((float4*)out)[i] = o;
    }
}

// ---------------- launch ----------------
extern "C" void kernel_launch(void* const* d_in, const int* in_sizes, int n_in,
                              void* d_out, int out_size, void* d_ws, size_t ws_size,
                              hipStream_t stream)
{
    const float* feature = (const float*)d_in[0];
    const int* ei        = (const int*)d_in[1];
    const float* Wl   = (const float*)d_in[2];
    const float* bl   = (const float*)d_in[3];
    const float* Wr   = (const float*)d_in[4];
    const float* br   = (const float*)d_in[5];
    const float* att  = (const float*)d_in[6];
    const float* bias = (const float*)d_in[7];
    const float* gamma = (const float*)d_in[8];
    const float* beta  = (const float*)d_in[9];

    const int n = in_sizes[0] / IN_DIM;
    const int E = in_sizes[1] / 2;
    const int Etot = E + n;
    const int ntiles = (n + 15) / 16;

    char* ws = (char*)d_ws;
    size_t o = 0;
    auto carve = [&](size_t bytes) -> void* {
        void* p = ws + o; o = (o + bytes + 15) & ~(size_t)15; return p;
    };
    unsigned short* xl    = (unsigned short*)carve((size_t)n * HC * sizeof(short));
    unsigned short* xr    = (unsigned short*)carve((size_t)n * HC * sizeof(short));
    unsigned short* Afrag = (unsigned short*)carve((size_t)ntiles * 4 * 64 * 8 * sizeof(short));
    unsigned short* Wfrag = (unsigned short*)carve((size_t)32 * 4 * 64 * 8 * sizeof(short));
    int*   csr_src = (int*)carve((size_t)Etot * sizeof(int));
    int*   cnt     = (int*)carve((size_t)n * sizeof(int));
    int*   off     = (int*)carve((size_t)(n + 1) * sizeof(int));
    int*   cur     = (int*)carve((size_t)n * sizeof(int));
    float* partials = (float*)carve((size_t)NB_BN * 512 * sizeof(float));
    float* stats   = (float*)carve(512 * sizeof(float));
    float* outf = (float*)d_out;

    if (o > ws_size) return;

    // 1. fragment casts + MFMA projections
    cast_w<<<128, 64, 0, stream>>>(Wl, Wr, Wfrag);
    cast_a<<<ntiles, 256, 0, stream>>>(feature, Afrag, n);
    gemm_mfma<<<(ntiles + 3) / 4, 256, 0, stream>>>(Afrag, Wfrag, bl, br, xl, xr, n, ntiles);

    // 2. CSR by dst
    hipMemsetAsync(cnt, 0, (size_t)n * sizeof(int), stream);
    hist_kernel<<<2048, 256, 0, stream>>>(ei, cnt, E, n);
    scan_kernel<<<1, 1024, 0, stream>>>(cnt, off, cur, n);
    fill_kernel<<<2048, 256, 0, stream>>>(ei, cur, csr_src, E, n);

    // 3. per-node online-softmax aggregation
    int agg_blocks = (n + 3) / 4;
    gat_agg<<<agg_blocks, 256, 0, stream>>>(xl, xr, csr_src, off, att, bias, outf, n);

    // 4. BatchNorm + ReLU
    bn_partial<<<NB_BN, 256, 0, stream>>>(outf, partials, n);
    bn_final<<<1, 256, 0, stream>>>(partials, stats, n);
    long long total4 = (long long)n * (HC / 4);
    bn_apply<<<2048, 256, 0, stream>>>(outf, stats, gamma, beta, total4);
}

// Round 4
// 555.925 us; speedup vs baseline: 1.8840x; 1.3879x over previous
//
#include <hip/hip_runtime.h>
#include <cstdint>

#define IN_DIM 128
#define HC 256          // H*C
#define NEG_SLOPE 0.2f
#define BN_EPS 1e-5f

typedef short bf16x8 __attribute__((ext_vector_type(8)));   // 8 bf16 = 4 VGPR
typedef float f32x4 __attribute__((ext_vector_type(4)));

__device__ __forceinline__ unsigned short f2bf(float f) {
    union { float f; unsigned int u; } v; v.f = f;
    unsigned int r = (v.u + 0x7FFFu + ((v.u >> 16) & 1u)) >> 16;   // RNE
    return (unsigned short)r;
}
__device__ __forceinline__ float bf2f(unsigned short h) {
    union { unsigned int u; float f; } v; v.u = ((unsigned int)h) << 16;
    return v.f;
}

// ---------- cast W -> fragment layout: Wfrag[((j*4+kk)*64+l)*8+m] = Wcat[k][col] ----------
__global__ __launch_bounds__(64) void cast_w(
    const float* __restrict__ Wl, const float* __restrict__ Wr,
    unsigned short* __restrict__ Wfrag)
{
    int j = blockIdx.x >> 2;          // 0..31
    int kk = blockIdx.x & 3;          // 0..3
    int l = threadIdx.x;              // 0..63
    int col = j * 16 + (l & 15);      // 0..511
    const float* W = (col < 256) ? Wl : Wr;
    int c = col & 255;
    unsigned short tmp[8];
#pragma unroll
    for (int m = 0; m < 8; ++m) {
        int k = kk * 32 + ((l >> 4) << 3) + m;
        tmp[m] = f2bf(W[(size_t)k * 256 + c]);
    }
    ulonglong2* dst = (ulonglong2*)(Wfrag + ((size_t)(j * 4 + kk) * 64 + l) * 8);
    *dst = *(ulonglong2*)tmp;
}

// ---------- cast A -> fragment layout ----------
__global__ __launch_bounds__(256) void cast_a(
    const float* __restrict__ A, unsigned short* __restrict__ Afrag, int n)
{
    int i = blockIdx.x;               // row tile
    int kk = threadIdx.x >> 6;        // wave id = k-chunk
    int l = threadIdx.x & 63;
    int row = i * 16 + (l & 15);
    int k0 = kk * 32 + ((l >> 4) << 3);
    float4 f0 = make_float4(0.f, 0.f, 0.f, 0.f), f1 = f0;
    if (row < n) {
        const float* p = A + (size_t)row * IN_DIM + k0;
        f0 = *(const float4*)p;
        f1 = *(const float4*)(p + 4);
    }
    unsigned short tmp[8];
    tmp[0] = f2bf(f0.x); tmp[1] = f2bf(f0.y); tmp[2] = f2bf(f0.z); tmp[3] = f2bf(f0.w);
    tmp[4] = f2bf(f1.x); tmp[5] = f2bf(f1.y); tmp[6] = f2bf(f1.z); tmp[7] = f2bf(f1.w);
    ulonglong2* dst = (ulonglong2*)(Afrag + ((size_t)(i * 4 + kk) * 64 + l) * 8);
    *dst = *(ulonglong2*)tmp;
}

// ---------- MFMA GEMM: xl/xr (bf16, row-major [n][256]) = A @ [Wl|Wr] + bias ----------
__global__ __launch_bounds__(256) void gemm_mfma(
    const unsigned short* __restrict__ Afrag, const unsigned short* __restrict__ Wfrag,
    const float* __restrict__ bl, const float* __restrict__ br,
    unsigned short* __restrict__ xl, unsigned short* __restrict__ xr,
    int n, int ntiles)
{
    int i = blockIdx.x * 4 + (threadIdx.x >> 6);   // row tile
    if (i >= ntiles) return;
    int l = threadIdx.x & 63;

    const bf16x8* av = (const bf16x8*)(Afrag + ((size_t)i * 4 * 64 + l) * 8);
    bf16x8 a0 = av[0 * 64], a1 = av[1 * 64], a2 = av[2 * 64], a3 = av[3 * 64];

    const bf16x8* wv = (const bf16x8*)Wfrag + l;
    int cl = l & 15;
    int rbase = i * 16 + ((l >> 4) << 2);

#pragma unroll 4
    for (int j = 0; j < 32; ++j) {
        const bf16x8* bp = wv + (size_t)j * 4 * 64;
        f32x4 acc = {0.f, 0.f, 0.f, 0.f};
        acc = __builtin_amdgcn_mfma_f32_16x16x32_bf16(a0, bp[0 * 64], acc, 0, 0, 0);
        acc = __builtin_amdgcn_mfma_f32_16x16x32_bf16(a1, bp[1 * 64], acc, 0, 0, 0);
        acc = __builtin_amdgcn_mfma_f32_16x16x32_bf16(a2, bp[2 * 64], acc, 0, 0, 0);
        acc = __builtin_amdgcn_mfma_f32_16x16x32_bf16(a3, bp[3 * 64], acc, 0, 0, 0);

        int col = j * 16 + cl;                 // 0..511
        unsigned short* X = (col < 256) ? xl : xr;
        int c = col & 255;
        float b = (col < 256) ? bl[c] : br[c];
#pragma unroll
        for (int q = 0; q < 4; ++q) {
            int row = rbase + q;
            if (row < n) X[(size_t)row * HC + c] = f2bf(acc[q] + b);
        }
    }
}

// ---------------- CSR build (edge_index int32: ei[0..E)=src, ei[E..2E)=dst) ----------
__global__ void hist_kernel(const int* __restrict__ ei, int* __restrict__ cnt,
                            int E, int n)
{
    int total = E + n;
    for (int e = blockIdx.x * blockDim.x + threadIdx.x; e < total;
         e += gridDim.x * blockDim.x) {
        int dst = (e < E) ? ei[(size_t)E + e] : (e - E);
        atomicAdd(&cnt[dst], 1);
    }
}

// -------- hierarchical scan: 256 blocks x 256 threads, ept elements/thread --------
#define SCAN_BLOCKS 256

__global__ __launch_bounds__(256) void scan_phaseA(const int* __restrict__ cnt,
                                                   int* __restrict__ blocksums,
                                                   int n, int ept)
{
    __shared__ int red[256];
    int t = threadIdx.x;
    int g = blockIdx.x * 256 + t;
    int beg = g * ept, end = min(beg + ept, n);
    int s = 0;
    for (int i = beg; i < end; ++i) s += cnt[i];
    red[t] = s;
    __syncthreads();
    for (int d = 128; d > 0; d >>= 1) {
        if (t < d) red[t] += red[t + d];
        __syncthreads();
    }
    if (t == 0) blocksums[blockIdx.x] = red[0];
}

__global__ __launch_bounds__(256) void scan_phaseB(const int* __restrict__ blocksums,
                                                   int* __restrict__ blockoffs,
                                                   int* __restrict__ off, int n)
{
    __shared__ int sums[256];
    int t = threadIdx.x;
    sums[t] = blocksums[t];
    __syncthreads();
    for (int d = 1; d < 256; d <<= 1) {
        int v = (t >= d) ? sums[t - d] : 0;
        __syncthreads();
        sums[t] += v;
        __syncthreads();
    }
    blockoffs[t] = (t == 0) ? 0 : sums[t - 1];
    if (t == 255) off[n] = sums[255];
}

__global__ __launch_bounds__(256) void scan_phaseC(const int* __restrict__ cnt,
                                                   const int* __restrict__ blockoffs,
                                                   int* __restrict__ off,
                                                   int* __restrict__ cur,
                                                   int n, int ept)
{
    __shared__ int sums[256];
    int t = threadIdx.x;
    int g = blockIdx.x * 256 + t;
    int beg = g * ept, end = min(beg + ept, n);
    int s = 0;
    for (int i = beg; i < end; ++i) s += cnt[i];
    sums[t] = s;
    __syncthreads();
    for (int d = 1; d < 256; d <<= 1) {
        int v = (t >= d) ? sums[t - d] : 0;
        __syncthreads();
        sums[t] += v;
        __syncthreads();
    }
    int run = blockoffs[blockIdx.x] + ((t == 0) ? 0 : sums[t - 1]);
    for (int i = beg; i < end; ++i) {
        int c = cnt[i];
        off[i] = run; cur[i] = run;
        run += c;
    }
}

__global__ void fill_kernel(const int* __restrict__ ei, int* __restrict__ cur,
                            int* __restrict__ csr_src, int E, int n)
{
    int total = E + n;
    for (int e = blockIdx.x * blockDim.x + threadIdx.x; e < total;
         e += gridDim.x * blockDim.x) {
        int src, dst;
        if (e < E) { src = ei[e]; dst = ei[(size_t)E + e]; }
        else       { src = dst = e - E; }
        int pos = atomicAdd(&cur[dst], 1);
        csr_src[pos] = src;
    }
}

// ---------------- per-node wave aggregation (online softmax, bf16 xl/xr) -----------
__global__ __launch_bounds__(256) void gat_agg(
    const unsigned short* __restrict__ xl, const unsigned short* __restrict__ xr,
    const int* __restrict__ csr_src, const int* __restrict__ off,
    const float* __restrict__ att, const float* __restrict__ bias,
    float* __restrict__ out, int n)
{
    int d = (blockIdx.x * blockDim.x + threadIdx.x) >> 6;   // one wave per node
    int lane = threadIdx.x & 63;
    if (d >= n) return;

    const ushort4* xlv = (const ushort4*)xl;
    ushort4 xru = ((const ushort4*)xr)[(size_t)d * 64 + lane];
    float xr0 = bf2f(xru.x), xr1 = bf2f(xru.y), xr2 = bf2f(xru.z), xr3 = bf2f(xru.w);
    float4 att4 = *(const float4*)(att + 4 * lane);

    int beg = off[d], end = off[d + 1];
    float m = -INFINITY;
    float lsum = 0.f;
    float ax = 0.f, ay = 0.f, az = 0.f, aw = 0.f;

    int i = beg;
    for (; i + 1 < end; i += 2) {
        int s0 = csr_src[i];
        int s1 = csr_src[i + 1];
        ushort4 u0 = xlv[(size_t)s0 * 64 + lane];
        ushort4 u1 = xlv[(size_t)s1 * 64 + lane];
        float f0x = bf2f(u0.x), f0y = bf2f(u0.y), f0z = bf2f(u0.z), f0w = bf2f(u0.w);
        float f1x = bf2f(u1.x), f1y = bf2f(u1.y), f1z = bf2f(u1.z), f1w = bf2f(u1.w);

        float z, p0, p1;
        z = f0x + xr0; p0  = att4.x * ((z > 0.f) ? z : NEG_SLOPE * z);
        z = f0y + xr1; p0 += att4.y * ((z > 0.f) ? z : NEG_SLOPE * z);
        z = f0z + xr2; p0 += att4.z * ((z > 0.f) ? z : NEG_SLOPE * z);
        z = f0w + xr3; p0 += att4.w * ((z > 0.f) ? z : NEG_SLOPE * z);
        z = f1x + xr0; p1  = att4.x * ((z > 0.f) ? z : NEG_SLOPE * z);
        z = f1y + xr1; p1 += att4.y * ((z > 0.f) ? z : NEG_SLOPE * z);
        z = f1z + xr2; p1 += att4.z * ((z > 0.f) ? z : NEG_SLOPE * z);
        z = f1w + xr3; p1 += att4.w * ((z > 0.f) ? z : NEG_SLOPE * z);

        p0 += __shfl_xor(p0, 1);  p1 += __shfl_xor(p1, 1);
        p0 += __shfl_xor(p0, 2);  p1 += __shfl_xor(p1, 2);
        p0 += __shfl_xor(p0, 4);  p1 += __shfl_xor(p1, 4);
        p0 += __shfl_xor(p0, 8);  p1 += __shfl_xor(p1, 8);

        float mx = fmaxf(p0, p1);
        if (mx > m) {
            float sc = __expf(m - mx);     // exp(-inf)=0 on first pair
            ax *= sc; ay *= sc; az *= sc; aw *= sc; lsum *= sc;
            m = mx;
        }
        float e0 = __expf(p0 - m);
        float e1 = __expf(p1 - m);
        ax += e0 * f0x + e1 * f1x;
        ay += e0 * f0y + e1 * f1y;
        az += e0 * f0z + e1 * f1z;
        aw += e0 * f0w + e1 * f1w;
        lsum += e0 + e1;
    }
    if (i < end) {
        int s0 = csr_src[i];
        ushort4 u0 = xlv[(size_t)s0 * 64 + lane];
        float f0x = bf2f(u0.x), f0y = bf2f(u0.y), f0z = bf2f(u0.z), f0w = bf2f(u0.w);
        float z, p0;
        z = f0x + xr0; p0  = att4.x * ((z > 0.f) ? z : NEG_SLOPE * z);
        z = f0y + xr1; p0 += att4.y * ((z > 0.f) ? z : NEG_SLOPE * z);
        z = f0z + xr2; p0 += att4.z * ((z > 0.f) ? z : NEG_SLOPE * z);
        z = f0w + xr3; p0 += att4.w * ((z > 0.f) ? z : NEG_SLOPE * z);
        p0 += __shfl_xor(p0, 1);
        p0 += __shfl_xor(p0, 2);
        p0 += __shfl_xor(p0, 4);
        p0 += __shfl_xor(p0, 8);
        if (p0 > m) {
            float sc = __expf(m - p0);
            ax *= sc; ay *= sc; az *= sc; aw *= sc; lsum *= sc;
            m = p0;
        }
        float e0 = __expf(p0 - m);
        ax += e0 * f0x; ay += e0 * f0y; az += e0 * f0z; aw += e0 * f0w;
        lsum += e0;
    }

    float inv = 1.f / (lsum + 1e-16f);
    float4 b4 = *(const float4*)(bias + 4 * lane);
    float4 o;
    o.x = ax * inv + b4.x; o.y = ay * inv + b4.y;
    o.z = az * inv + b4.z; o.w = aw * inv + b4.w;
    *(float4*)(out + (size_t)d * HC + 4 * lane) = o;
}

// ---------------- BatchNorm ----------------
#define NB_BN 512
__global__ __launch_bounds__(256) void bn_partial(const float* __restrict__ out,
                                                  float* __restrict__ partials, int n)
{
    int c = threadIdx.x;
    int b = blockIdx.x;
    int chunk = (n + NB_BN - 1) / NB_BN;
    int beg = b * chunk;
    int end = min(beg + chunk, n);
    float s = 0.f, s2 = 0.f;
    for (int r = beg; r < end; ++r) {
        float v = out[(size_t)r * HC + c];
        s += v; s2 += v * v;
    }
    partials[(size_t)b * 512 + c] = s;
    partials[(size_t)b * 512 + 256 + c] = s2;
}

__global__ __launch_bounds__(256) void bn_final(const float* __restrict__ partials,
                                                float* __restrict__ stats, int n)
{
    int c = threadIdx.x;
    float s = 0.f, s2 = 0.f;
    for (int b = 0; b < NB_BN; ++b) {
        s += partials[(size_t)b * 512 + c];
        s2 += partials[(size_t)b * 512 + 256 + c];
    }
    float mean = s / (float)n;
    float var = s2 / (float)n - mean * mean;
    stats[c] = mean;
    stats[256 + c] = rsqrtf(var + BN_EPS);
}

__global__ void bn_apply(float* __restrict__ out, const float* __restrict__ stats,
                         const float* __restrict__ gamma, const float* __restrict__ beta,
                         long long total4)
{
    long long stride = (long long)gridDim.x * blockDim.x;
    for (long long i = blockIdx.x * (long long)blockDim.x + threadIdx.x; i < total4;
         i += stride) {
        int cb = ((int)(i & 63)) * 4;
        float4 v = ((const float4*)out)[i];
        float4 o;
        o.x = fmaxf(0.f, (v.x - stats[cb + 0]) * stats[256 + cb + 0] * gamma[cb + 0] + beta[cb + 0]);
        o.y = fmaxf(0.f, (v.y - stats[cb + 1]) * stats[256 + cb + 1] * gamma[cb + 1] + beta[cb + 1]);
        o.z = fmaxf(0.f, (v.z - stats[cb + 2]) * stats[256 + cb + 2] * gamma[cb + 2] + beta[cb + 2]);
        o.w = fmaxf(0.f, (v.w - stats[cb + 3]) * stats[256 + cb + 3] * gamma[cb + 3] + beta[cb + 3]);
        ((float4*)out)[i] = o;
    }
}

// ---------------- launch ----------------
extern "C" void kernel_launch(void* const* d_in, const int* in_sizes, int n_in,
                              void* d_out, int out_size, void* d_ws, size_t ws_size,
                              hipStream_t stream)
{
    const float* feature = (const float*)d_in[0];
    const int* ei        = (const int*)d_in[1];
    const float* Wl   = (const float*)d_in[2];
    const float* bl   = (const float*)d_in[3];
    const float* Wr   = (const float*)d_in[4];
    const float* br   = (const float*)d_in[5];
    const float* att  = (const float*)d_in[6];
    const float* bias = (const float*)d_in[7];
    const float* gamma = (const float*)d_in[8];
    const float* beta  = (const float*)d_in[9];

    const int n = in_sizes[0] / IN_DIM;
    const int E = in_sizes[1] / 2;
    const int Etot = E + n;
    const int ntiles = (n + 15) / 16;

    char* ws = (char*)d_ws;
    size_t o = 0;
    auto carve = [&](size_t bytes) -> void* {
        void* p = ws + o; o = (o + bytes + 15) & ~(size_t)15; return p;
    };
    unsigned short* xl    = (unsigned short*)carve((size_t)n * HC * sizeof(short));
    unsigned short* xr    = (unsigned short*)carve((size_t)n * HC * sizeof(short));
    unsigned short* Afrag = (unsigned short*)carve((size_t)ntiles * 4 * 64 * 8 * sizeof(short));
    unsigned short* Wfrag = (unsigned short*)carve((size_t)32 * 4 * 64 * 8 * sizeof(short));
    int*   csr_src = (int*)carve((size_t)Etot * sizeof(int));
    int*   cnt     = (int*)carve((size_t)n * sizeof(int));
    int*   off     = (int*)carve((size_t)(n + 1) * sizeof(int));
    int*   cur     = (int*)carve((size_t)n * sizeof(int));
    int*   blocksums = (int*)carve(SCAN_BLOCKS * sizeof(int));
    int*   blockoffs = (int*)carve(SCAN_BLOCKS * sizeof(int));
    float* partials = (float*)carve((size_t)NB_BN * 512 * sizeof(float));
    float* stats   = (float*)carve(512 * sizeof(float));
    float* outf = (float*)d_out;

    if (o > ws_size) return;

    // 1. fragment casts + MFMA projections
    cast_w<<<128, 64, 0, stream>>>(Wl, Wr, Wfrag);
    cast_a<<<ntiles, 256, 0, stream>>>(feature, Afrag, n);
    gemm_mfma<<<(ntiles + 3) / 4, 256, 0, stream>>>(Afrag, Wfrag, bl, br, xl, xr, n, ntiles);

    // 2. CSR by dst (hierarchical scan)
    hipMemsetAsync(cnt, 0, (size_t)n * sizeof(int), stream);
    hist_kernel<<<2048, 256, 0, stream>>>(ei, cnt, E, n);
    int ept = (n + SCAN_BLOCKS * 256 - 1) / (SCAN_BLOCKS * 256);
    scan_phaseA<<<SCAN_BLOCKS, 256, 0, stream>>>(cnt, blocksums, n, ept);
    scan_phaseB<<<1, 256, 0, stream>>>(blocksums, blockoffs, off, n);
    scan_phaseC<<<SCAN_BLOCKS, 256, 0, stream>>>(cnt, blockoffs, off, cur, n, ept);
    fill_kernel<<<2048, 256, 0, stream>>>(ei, cur, csr_src, E, n);

    // 3. per-node online-softmax aggregation
    int agg_blocks = (n + 3) / 4;
    gat_agg<<<agg_blocks, 256, 0, stream>>>(xl, xr, csr_src, off, att, bias, outf, n);

    // 4. BatchNorm + ReLU
    bn_partial<<<NB_BN, 256, 0, stream>>>(outf, partials, n);
    bn_final<<<1, 256, 0, stream>>>(partials, stats, n);
    long long total4 = (long long)n * (HC / 4);
    bn_apply<<<2048, 256, 0, stream>>>(outf, stats, gamma, beta, total4);
}

// Round 5
// 514.573 us; speedup vs baseline: 2.0354x; 1.0804x over previous
//
#include <hip/hip_runtime.h>
#include <cstdint>

#define IN_DIM 128
#define HC 256          // H*C
#define NEG_SLOPE 0.2f
#define BN_EPS 1e-5f

typedef short bf16x8 __attribute__((ext_vector_type(8)));   // 8 bf16 = 4 VGPR
typedef float f32x4 __attribute__((ext_vector_type(4)));

__device__ __forceinline__ unsigned short f2bf(float f) {
    union { float f; unsigned int u; } v; v.f = f;
    unsigned int r = (v.u + 0x7FFFu + ((v.u >> 16) & 1u)) >> 16;   // RNE
    return (unsigned short)r;
}
__device__ __forceinline__ float bf2f(unsigned short h) {
    union { unsigned int u; float f; } v; v.u = ((unsigned int)h) << 16;
    return v.f;
}

// DPP 16-lane sum butterfly step: x += dpp_perm(x). Pure VALU, no LDS.
template<int CTRL>
__device__ __forceinline__ float dppadd(float x) {
    int y = __builtin_amdgcn_update_dpp(0, __builtin_bit_cast(int, x), CTRL, 0xF, 0xF, true);
    return x + __builtin_bit_cast(float, y);
}
// full 16-lane reduction: quad xor1 (0xB1), quad xor2 (0x4E), row_ror:4, row_ror:8
__device__ __forceinline__ float red16(float p) {
    p = dppadd<0xB1>(p);
    p = dppadd<0x4E>(p);
    p = dppadd<0x124>(p);
    p = dppadd<0x128>(p);
    return p;
}

__device__ __forceinline__ void unpk(ushort4 u, float* f) {
    f[0] = bf2f(u.x); f[1] = bf2f(u.y); f[2] = bf2f(u.z); f[3] = bf2f(u.w);
}
__device__ __forceinline__ float esc(const float* f, float x0, float x1, float x2, float x3,
                                     float4 a) {
    float z0 = f[0] + x0, z1 = f[1] + x1, z2 = f[2] + x2, z3 = f[3] + x3;
    float p = a.x * fmaxf(z0, NEG_SLOPE * z0);
    p = fmaf(a.y, fmaxf(z1, NEG_SLOPE * z1), p);
    p = fmaf(a.z, fmaxf(z2, NEG_SLOPE * z2), p);
    p = fmaf(a.w, fmaxf(z3, NEG_SLOPE * z3), p);
    return p;
}

// ---------- cast W -> fragment layout: Wfrag[((j*4+kk)*64+l)*8+m] = Wcat[k][col] ----------
__global__ __launch_bounds__(64) void cast_w(
    const float* __restrict__ Wl, const float* __restrict__ Wr,
    unsigned short* __restrict__ Wfrag)
{
    int j = blockIdx.x >> 2;          // 0..31
    int kk = blockIdx.x & 3;          // 0..3
    int l = threadIdx.x;              // 0..63
    int col = j * 16 + (l & 15);      // 0..511
    const float* W = (col < 256) ? Wl : Wr;
    int c = col & 255;
    unsigned short tmp[8];
#pragma unroll
    for (int m = 0; m < 8; ++m) {
        int k = kk * 32 + ((l >> 4) << 3) + m;
        tmp[m] = f2bf(W[(size_t)k * 256 + c]);
    }
    ulonglong2* dst = (ulonglong2*)(Wfrag + ((size_t)(j * 4 + kk) * 64 + l) * 8);
    *dst = *(ulonglong2*)tmp;
}

// ---------- cast A -> fragment layout ----------
__global__ __launch_bounds__(256) void cast_a(
    const float* __restrict__ A, unsigned short* __restrict__ Afrag, int n)
{
    int i = blockIdx.x;               // row tile
    int kk = threadIdx.x >> 6;        // wave id = k-chunk
    int l = threadIdx.x & 63;
    int row = i * 16 + (l & 15);
    int k0 = kk * 32 + ((l >> 4) << 3);
    float4 f0 = make_float4(0.f, 0.f, 0.f, 0.f), f1 = f0;
    if (row < n) {
        const float* p = A + (size_t)row * IN_DIM + k0;
        f0 = *(const float4*)p;
        f1 = *(const float4*)(p + 4);
    }
    unsigned short tmp[8];
    tmp[0] = f2bf(f0.x); tmp[1] = f2bf(f0.y); tmp[2] = f2bf(f0.z); tmp[3] = f2bf(f0.w);
    tmp[4] = f2bf(f1.x); tmp[5] = f2bf(f1.y); tmp[6] = f2bf(f1.z); tmp[7] = f2bf(f1.w);
    ulonglong2* dst = (ulonglong2*)(Afrag + ((size_t)(i * 4 + kk) * 64 + l) * 8);
    *dst = *(ulonglong2*)tmp;
}

// ---------- MFMA GEMM: xl/xr (bf16, row-major [n][256]) = A @ [Wl|Wr] + bias ----------
__global__ __launch_bounds__(256) void gemm_mfma(
    const unsigned short* __restrict__ Afrag, const unsigned short* __restrict__ Wfrag,
    const float* __restrict__ bl, const float* __restrict__ br,
    unsigned short* __restrict__ xl, unsigned short* __restrict__ xr,
    int n, int ntiles)
{
    int i = blockIdx.x * 4 + (threadIdx.x >> 6);   // row tile
    if (i >= ntiles) return;
    int l = threadIdx.x & 63;

    const bf16x8* av = (const bf16x8*)(Afrag + ((size_t)i * 4 * 64 + l) * 8);
    bf16x8 a0 = av[0 * 64], a1 = av[1 * 64], a2 = av[2 * 64], a3 = av[3 * 64];

    const bf16x8* wv = (const bf16x8*)Wfrag + l;
    int cl = l & 15;
    int rbase = i * 16 + ((l >> 4) << 2);

#pragma unroll 4
    for (int j = 0; j < 32; ++j) {
        const bf16x8* bp = wv + (size_t)j * 4 * 64;
        f32x4 acc = {0.f, 0.f, 0.f, 0.f};
        acc = __builtin_amdgcn_mfma_f32_16x16x32_bf16(a0, bp[0 * 64], acc, 0, 0, 0);
        acc = __builtin_amdgcn_mfma_f32_16x16x32_bf16(a1, bp[1 * 64], acc, 0, 0, 0);
        acc = __builtin_amdgcn_mfma_f32_16x16x32_bf16(a2, bp[2 * 64], acc, 0, 0, 0);
        acc = __builtin_amdgcn_mfma_f32_16x16x32_bf16(a3, bp[3 * 64], acc, 0, 0, 0);

        int col = j * 16 + cl;                 // 0..511
        unsigned short* X = (col < 256) ? xl : xr;
        int c = col & 255;
        float b = (col < 256) ? bl[c] : br[c];
#pragma unroll
        for (int q = 0; q < 4; ++q) {
            int row = rbase + q;
            if (row < n) X[(size_t)row * HC + c] = f2bf(acc[q] + b);
        }
    }
}

// ---------------- CSR build (edge_index int32: ei[0..E)=src, ei[E..2E)=dst) ----------
__global__ void hist_kernel(const int* __restrict__ ei, int* __restrict__ cnt,
                            int E, int n)
{
    int total = E + n;
    for (int e = blockIdx.x * blockDim.x + threadIdx.x; e < total;
         e += gridDim.x * blockDim.x) {
        int dst = (e < E) ? ei[(size_t)E + e] : (e - E);
        atomicAdd(&cnt[dst], 1);
    }
}

// -------- hierarchical scan: 256 blocks x 256 threads, ept elements/thread --------
#define SCAN_BLOCKS 256

__global__ __launch_bounds__(256) void scan_phaseA(const int* __restrict__ cnt,
                                                   int* __restrict__ blocksums,
                                                   int n, int ept)
{
    __shared__ int red[256];
    int t = threadIdx.x;
    int g = blockIdx.x * 256 + t;
    int beg = g * ept, end = min(beg + ept, n);
    int s = 0;
    for (int i = beg; i < end; ++i) s += cnt[i];
    red[t] = s;
    __syncthreads();
    for (int d = 128; d > 0; d >>= 1) {
        if (t < d) red[t] += red[t + d];
        __syncthreads();
    }
    if (t == 0) blocksums[blockIdx.x] = red[0];
}

__global__ __launch_bounds__(256) void scan_phaseB(const int* __restrict__ blocksums,
                                                   int* __restrict__ blockoffs,
                                                   int* __restrict__ off, int n)
{
    __shared__ int sums[256];
    int t = threadIdx.x;
    sums[t] = blocksums[t];
    __syncthreads();
    for (int d = 1; d < 256; d <<= 1) {
        int v = (t >= d) ? sums[t - d] : 0;
        __syncthreads();
        sums[t] += v;
        __syncthreads();
    }
    blockoffs[t] = (t == 0) ? 0 : sums[t - 1];
    if (t == 255) off[n] = sums[255];
}

__global__ __launch_bounds__(256) void scan_phaseC(const int* __restrict__ cnt,
                                                   const int* __restrict__ blockoffs,
                                                   int* __restrict__ off,
                                                   int* __restrict__ cur,
                                                   int n, int ept)
{
    __shared__ int sums[256];
    int t = threadIdx.x;
    int g = blockIdx.x * 256 + t;
    int beg = g * ept, end = min(beg + ept, n);
    int s = 0;
    for (int i = beg; i < end; ++i) s += cnt[i];
    sums[t] = s;
    __syncthreads();
    for (int d = 1; d < 256; d <<= 1) {
        int v = (t >= d) ? sums[t - d] : 0;
        __syncthreads();
        sums[t] += v;
        __syncthreads();
    }
    int run = blockoffs[blockIdx.x] + ((t == 0) ? 0 : sums[t - 1]);
    for (int i = beg; i < end; ++i) {
        int c = cnt[i];
        off[i] = run; cur[i] = run;
        run += c;
    }
}

// stores BYTE offsets of the source row (src*512) to cut gather address math
__global__ void fill_kernel(const int* __restrict__ ei, int* __restrict__ cur,
                            int* __restrict__ csr_boff, int E, int n)
{
    int total = E + n;
    for (int e = blockIdx.x * blockDim.x + threadIdx.x; e < total;
         e += gridDim.x * blockDim.x) {
        int src, dst;
        if (e < E) { src = ei[e]; dst = ei[(size_t)E + e]; }
        else       { src = dst = e - E; }
        int pos = atomicAdd(&cur[dst], 1);
        csr_boff[pos] = src << 9;          // src * 512 bytes (bf16 row)
    }
}

// ---------------- per-node wave aggregation (online softmax, bf16 xl/xr) -----------
__global__ __launch_bounds__(256) void gat_agg(
    const unsigned short* __restrict__ xl, const unsigned short* __restrict__ xr,
    const int* __restrict__ csr_boff, const int* __restrict__ off,
    const float* __restrict__ att, const float* __restrict__ bias,
    float* __restrict__ out, int n)
{
    int d = (blockIdx.x * blockDim.x + threadIdx.x) >> 6;   // one wave per node
    int lane = threadIdx.x & 63;
    if (d >= n) return;

    const char* xlb = (const char*)xl + (lane << 3);        // + row byte-offset per edge
    ushort4 xru = ((const ushort4*)xr)[(size_t)d * 64 + lane];
    float xr0 = bf2f(xru.x), xr1 = bf2f(xru.y), xr2 = bf2f(xru.z), xr3 = bf2f(xru.w);
    float4 att4 = *(const float4*)(att + 4 * lane);

    int beg = off[d], end = off[d + 1];
    float m = -INFINITY;
    float lsum = 0.f;
    float ax = 0.f, ay = 0.f, az = 0.f, aw = 0.f;

    int i = beg;
    for (; i + 3 < end; i += 4) {
        int b0 = csr_boff[i], b1 = csr_boff[i + 1];
        int b2 = csr_boff[i + 2], b3 = csr_boff[i + 3];
        ushort4 u0 = *(const ushort4*)(xlb + b0);
        ushort4 u1 = *(const ushort4*)(xlb + b1);
        ushort4 u2 = *(const ushort4*)(xlb + b2);
        ushort4 u3 = *(const ushort4*)(xlb + b3);
        float f0[4], f1[4], f2[4], f3[4];
        unpk(u0, f0); unpk(u1, f1); unpk(u2, f2); unpk(u3, f3);

        float p0 = esc(f0, xr0, xr1, xr2, xr3, att4);
        float p1 = esc(f1, xr0, xr1, xr2, xr3, att4);
        float p2 = esc(f2, xr0, xr1, xr2, xr3, att4);
        float p3 = esc(f3, xr0, xr1, xr2, xr3, att4);

        // four interleaved 16-lane DPP reductions (per-head)
        p0 = dppadd<0xB1>(p0);  p1 = dppadd<0xB1>(p1);  p2 = dppadd<0xB1>(p2);  p3 = dppadd<0xB1>(p3);
        p0 = dppadd<0x4E>(p0);  p1 = dppadd<0x4E>(p1);  p2 = dppadd<0x4E>(p2);  p3 = dppadd<0x4E>(p3);
        p0 = dppadd<0x124>(p0); p1 = dppadd<0x124>(p1); p2 = dppadd<0x124>(p2); p3 = dppadd<0x124>(p3);
        p0 = dppadd<0x128>(p0); p1 = dppadd<0x128>(p1); p2 = dppadd<0x128>(p2); p3 = dppadd<0x128>(p3);

        float mx = fmaxf(fmaxf(p0, p1), fmaxf(p2, p3));
        if (mx > m) {                      // rarely taken after warm-up
            float sc = __expf(m - mx);     // exp(-inf)=0 on first group
            ax *= sc; ay *= sc; az *= sc; aw *= sc; lsum *= sc;
            m = mx;
        }
        float e0 = __expf(p0 - m), e1 = __expf(p1 - m);
        float e2 = __expf(p2 - m), e3 = __expf(p3 - m);
        ax = fmaf(e0, f0[0], fmaf(e1, f1[0], fmaf(e2, f2[0], fmaf(e3, f3[0], ax))));
        ay = fmaf(e0, f0[1], fmaf(e1, f1[1], fmaf(e2, f2[1], fmaf(e3, f3[1], ay))));
        az = fmaf(e0, f0[2], fmaf(e1, f1[2], fmaf(e2, f2[2], fmaf(e3, f3[2], az))));
        aw = fmaf(e0, f0[3], fmaf(e1, f1[3], fmaf(e2, f2[3], fmaf(e3, f3[3], aw))));
        lsum += (e0 + e1) + (e2 + e3);
    }
    for (; i < end; ++i) {                 // tail (0..3 edges)
        int b0 = csr_boff[i];
        ushort4 u0 = *(const ushort4*)(xlb + b0);
        float f0[4];
        unpk(u0, f0);
        float p0 = esc(f0, xr0, xr1, xr2, xr3, att4);
        p0 = red16(p0);
        if (p0 > m) {
            float sc = __expf(m - p0);
            ax *= sc; ay *= sc; az *= sc; aw *= sc; lsum *= sc;
            m = p0;
        }
        float e0 = __expf(p0 - m);
        ax = fmaf(e0, f0[0], ax); ay = fmaf(e0, f0[1], ay);
        az = fmaf(e0, f0[2], az); aw = fmaf(e0, f0[3], aw);
        lsum += e0;
    }

    float inv = 1.f / (lsum + 1e-16f);
    float4 b4 = *(const float4*)(bias + 4 * lane);
    float4 o;
    o.x = fmaf(ax, inv, b4.x); o.y = fmaf(ay, inv, b4.y);
    o.z = fmaf(az, inv, b4.z); o.w = fmaf(aw, inv, b4.w);
    *(float4*)(out + (size_t)d * HC + 4 * lane) = o;
}

// ---------------- BatchNorm ----------------
#define NB_BN 512
__global__ __launch_bounds__(256) void bn_partial(const float* __restrict__ out,
                                                  float* __restrict__ partials, int n)
{
    int c = threadIdx.x;
    int b = blockIdx.x;
    int chunk = (n + NB_BN - 1) / NB_BN;
    int beg = b * chunk;
    int end = min(beg + chunk, n);
    float s = 0.f, s2 = 0.f;
    for (int r = beg; r < end; ++r) {
        float v = out[(size_t)r * HC + c];
        s += v; s2 += v * v;
    }
    partials[(size_t)b * 512 + c] = s;
    partials[(size_t)b * 512 + 256 + c] = s2;
}

// one block per channel: 256 threads sum NB_BN partials -> LDS tree -> stats
__global__ __launch_bounds__(256) void bn_final(const float* __restrict__ partials,
                                                float* __restrict__ stats, int n)
{
    int c = blockIdx.x;           // 0..255
    int t = threadIdx.x;
    float s = 0.f, s2 = 0.f;
    for (int b = t; b < NB_BN; b += 256) {
        s  += partials[(size_t)b * 512 + c];
        s2 += partials[(size_t)b * 512 + 256 + c];
    }
    __shared__ float rs[256], rs2[256];
    rs[t] = s; rs2[t] = s2;
    __syncthreads();
    for (int d = 128; d > 0; d >>= 1) {
        if (t < d) { rs[t] += rs[t + d]; rs2[t] += rs2[t + d]; }
        __syncthreads();
    }
    if (t == 0) {
        float mean = rs[0] / (float)n;
        float var = rs2[0] / (float)n - mean * mean;
        stats[c] = mean;
        stats[256 + c] = rsqrtf(var + BN_EPS);
    }
}

__global__ void bn_apply(float* __restrict__ out, const float* __restrict__ stats,
                         const float* __restrict__ gamma, const float* __restrict__ beta,
                         long long total4)
{
    long long stride = (long long)gridDim.x * blockDim.x;
    for (long long i = blockIdx.x * (long long)blockDim.x + threadIdx.x; i < total4;
         i += stride) {
        int cb = ((int)(i & 63)) * 4;
        float4 v = ((const float4*)out)[i];
        float4 o;
        o.x = fmaxf(0.f, (v.x - stats[cb + 0]) * stats[256 + cb + 0] * gamma[cb + 0] + beta[cb + 0]);
        o.y = fmaxf(0.f, (v.y - stats[cb + 1]) * stats[256 + cb + 1] * gamma[cb + 1] + beta[cb + 1]);
        o.z = fmaxf(0.f, (v.z - stats[cb + 2]) * stats[256 + cb + 2] * gamma[cb + 2] + beta[cb + 2]);
        o.w = fmaxf(0.f, (v.w - stats[cb + 3]) * stats[256 + cb + 3] * gamma[cb + 3] + beta[cb + 3]);
        ((float4*)out)[i] = o;
    }
}

// ---------------- launch ----------------
extern "C" void kernel_launch(void* const* d_in, const int* in_sizes, int n_in,
                              void* d_out, int out_size, void* d_ws, size_t ws_size,
                              hipStream_t stream)
{
    const float* feature = (const float*)d_in[0];
    const int* ei        = (const int*)d_in[1];
    const float* Wl   = (const float*)d_in[2];
    const float* bl   = (const float*)d_in[3];
    const float* Wr   = (const float*)d_in[4];
    const float* br   = (const float*)d_in[5];
    const float* att  = (const float*)d_in[6];
    const float* bias = (const float*)d_in[7];
    const float* gamma = (const float*)d_in[8];
    const float* beta  = (const float*)d_in[9];

    const int n = in_sizes[0] / IN_DIM;
    const int E = in_sizes[1] / 2;
    const int Etot = E + n;
    const int ntiles = (n + 15) / 16;

    char* ws = (char*)d_ws;
    size_t o = 0;
    auto carve = [&](size_t bytes) -> void* {
        void* p = ws + o; o = (o + bytes + 15) & ~(size_t)15; return p;
    };
    unsigned short* xl    = (unsigned short*)carve((size_t)n * HC * sizeof(short));
    unsigned short* xr    = (unsigned short*)carve((size_t)n * HC * sizeof(short));
    unsigned short* Afrag = (unsigned short*)carve((size_t)ntiles * 4 * 64 * 8 * sizeof(short));
    unsigned short* Wfrag = (unsigned short*)carve((size_t)32 * 4 * 64 * 8 * sizeof(short));
    int*   csr_boff = (int*)carve((size_t)Etot * sizeof(int));
    int*   cnt     = (int*)carve((size_t)n * sizeof(int));
    int*   off     = (int*)carve((size_t)(n + 1) * sizeof(int));
    int*   cur     = (int*)carve((size_t)n * sizeof(int));
    int*   blocksums = (int*)carve(SCAN_BLOCKS * sizeof(int));
    int*   blockoffs = (int*)carve(SCAN_BLOCKS * sizeof(int));
    float* partials = (float*)carve((size_t)NB_BN * 512 * sizeof(float));
    float* stats   = (float*)carve(512 * sizeof(float));
    float* outf = (float*)d_out;

    if (o > ws_size) return;

    // 1. fragment casts + MFMA projections
    cast_w<<<128, 64, 0, stream>>>(Wl, Wr, Wfrag);
    cast_a<<<ntiles, 256, 0, stream>>>(feature, Afrag, n);
    gemm_mfma<<<(ntiles + 3) / 4, 256, 0, stream>>>(Afrag, Wfrag, bl, br, xl, xr, n, ntiles);

    // 2. CSR by dst (hierarchical scan)
    hipMemsetAsync(cnt, 0, (size_t)n * sizeof(int), stream);
    hist_kernel<<<2048, 256, 0, stream>>>(ei, cnt, E, n);
    int ept = (n + SCAN_BLOCKS * 256 - 1) / (SCAN_BLOCKS * 256);
    scan_phaseA<<<SCAN_BLOCKS, 256, 0, stream>>>(cnt, blocksums, n, ept);
    scan_phaseB<<<1, 256, 0, stream>>>(blocksums, blockoffs, off, n);
    scan_phaseC<<<SCAN_BLOCKS, 256, 0, stream>>>(cnt, blockoffs, off, cur, n, ept);
    fill_kernel<<<2048, 256, 0, stream>>>(ei, cur, csr_boff, E, n);

    // 3. per-node online-softmax aggregation
    int agg_blocks = (n + 3) / 4;
    gat_agg<<<agg_blocks, 256, 0, stream>>>(xl, xr, csr_boff, off, att, bias, outf, n);

    // 4. BatchNorm + ReLU
    bn_partial<<<NB_BN, 256, 0, stream>>>(outf, partials, n);
    bn_final<<<256, 256, 0, stream>>>(partials, stats, n);
    long long total4 = (long long)n * (HC / 4);
    bn_apply<<<2048, 256, 0, stream>>>(outf, stats, gamma, beta, total4);
}

// Round 7
// 390.858 us; speedup vs baseline: 2.6796x; 1.3165x over previous
//
#include <hip/hip_runtime.h>
#include <cstdint>

#define IN_DIM 128
#define HC 256          // H*C
#define NEG_SLOPE 0.2f
#define BN_EPS 1e-5f
#define LOG2E 1.44269504088896340736f

typedef short bf16x8 __attribute__((ext_vector_type(8)));   // 8 bf16 = 4 VGPR
typedef float f32x4 __attribute__((ext_vector_type(4)));

// native v_exp_f32: computes 2^x
#define EXP2F(x) __builtin_amdgcn_exp2f(x)

__device__ __forceinline__ unsigned short f2bf(float f) {
    union { float f; unsigned int u; } v; v.f = f;
    unsigned int r = (v.u + 0x7FFFu + ((v.u >> 16) & 1u)) >> 16;   // RNE
    return (unsigned short)r;
}
__device__ __forceinline__ float bf2f(unsigned short h) {
    union { unsigned int u; float f; } v; v.u = ((unsigned int)h) << 16;
    return v.f;
}

// DPP 16-lane sum butterfly step: x += dpp_perm(x). Pure VALU, no LDS.
template<int CTRL>
__device__ __forceinline__ float dppadd(float x) {
    int y = __builtin_amdgcn_update_dpp(0, __builtin_bit_cast(int, x), CTRL, 0xF, 0xF, true);
    return x + __builtin_bit_cast(float, y);
}
__device__ __forceinline__ float red16(float p) {
    p = dppadd<0xB1>(p);
    p = dppadd<0x4E>(p);
    p = dppadd<0x124>(p);
    p = dppadd<0x128>(p);
    return p;
}

__device__ __forceinline__ void unpk(ushort4 u, float* f) {
    f[0] = bf2f(u.x); f[1] = bf2f(u.y); f[2] = bf2f(u.z); f[3] = bf2f(u.w);
}
// att pre-scaled by log2e -> result is in log2 domain
__device__ __forceinline__ float esc(const float* f, float x0, float x1, float x2, float x3,
                                     float4 a) {
    float z0 = f[0] + x0, z1 = f[1] + x1, z2 = f[2] + x2, z3 = f[3] + x3;
    float p = a.x * fmaxf(z0, NEG_SLOPE * z0);
    p = fmaf(a.y, fmaxf(z1, NEG_SLOPE * z1), p);
    p = fmaf(a.z, fmaxf(z2, NEG_SLOPE * z2), p);
    p = fmaf(a.w, fmaxf(z3, NEG_SLOPE * z3), p);
    return p;
}

// ---------- cast W -> fragment layout: Wfrag[((j*4+kk)*64+l)*8+m] = Wcat[k][col] ----------
__global__ __launch_bounds__(64) void cast_w(
    const float* __restrict__ Wl, const float* __restrict__ Wr,
    unsigned short* __restrict__ Wfrag)
{
    int j = blockIdx.x >> 2;          // 0..31
    int kk = blockIdx.x & 3;          // 0..3
    int l = threadIdx.x;              // 0..63
    int col = j * 16 + (l & 15);      // 0..511
    const float* W = (col < 256) ? Wl : Wr;
    int c = col & 255;
    unsigned short tmp[8];
#pragma unroll
    for (int m = 0; m < 8; ++m) {
        int k = kk * 32 + ((l >> 4) << 3) + m;
        tmp[m] = f2bf(W[(size_t)k * 256 + c]);
    }
    ulonglong2* dst = (ulonglong2*)(Wfrag + ((size_t)(j * 4 + kk) * 64 + l) * 8);
    *dst = *(ulonglong2*)tmp;
}

// ---------- cast A -> fragment layout ----------
__global__ __launch_bounds__(256) void cast_a(
    const float* __restrict__ A, unsigned short* __restrict__ Afrag, int n)
{
    int i = blockIdx.x;               // row tile
    int kk = threadIdx.x >> 6;        // wave id = k-chunk
    int l = threadIdx.x & 63;
    int row = i * 16 + (l & 15);
    int k0 = kk * 32 + ((l >> 4) << 3);
    float4 f0 = make_float4(0.f, 0.f, 0.f, 0.f), f1 = f0;
    if (row < n) {
        const float* p = A + (size_t)row * IN_DIM + k0;
        f0 = *(const float4*)p;
        f1 = *(const float4*)(p + 4);
    }
    unsigned short tmp[8];
    tmp[0] = f2bf(f0.x); tmp[1] = f2bf(f0.y); tmp[2] = f2bf(f0.z); tmp[3] = f2bf(f0.w);
    tmp[4] = f2bf(f1.x); tmp[5] = f2bf(f1.y); tmp[6] = f2bf(f1.z); tmp[7] = f2bf(f1.w);
    ulonglong2* dst = (ulonglong2*)(Afrag + ((size_t)(i * 4 + kk) * 64 + l) * 8);
    *dst = *(ulonglong2*)tmp;
}

// ---------- MFMA GEMM: xl/xr (bf16, row-major [n][256]) = A @ [Wl|Wr] + bias ----------
__global__ __launch_bounds__(256) void gemm_mfma(
    const unsigned short* __restrict__ Afrag, const unsigned short* __restrict__ Wfrag,
    const float* __restrict__ bl, const float* __restrict__ br,
    unsigned short* __restrict__ xl, unsigned short* __restrict__ xr,
    int n, int ntiles)
{
    int i = blockIdx.x * 4 + (threadIdx.x >> 6);   // row tile
    if (i >= ntiles) return;
    int l = threadIdx.x & 63;

    const bf16x8* av = (const bf16x8*)(Afrag + ((size_t)i * 4 * 64 + l) * 8);
    bf16x8 a0 = av[0 * 64], a1 = av[1 * 64], a2 = av[2 * 64], a3 = av[3 * 64];

    const bf16x8* wv = (const bf16x8*)Wfrag + l;
    int cl = l & 15;
    int rbase = i * 16 + ((l >> 4) << 2);

#pragma unroll 4
    for (int j = 0; j < 32; ++j) {
        const bf16x8* bp = wv + (size_t)j * 4 * 64;
        f32x4 acc = {0.f, 0.f, 0.f, 0.f};
        acc = __builtin_amdgcn_mfma_f32_16x16x32_bf16(a0, bp[0 * 64], acc, 0, 0, 0);
        acc = __builtin_amdgcn_mfma_f32_16x16x32_bf16(a1, bp[1 * 64], acc, 0, 0, 0);
        acc = __builtin_amdgcn_mfma_f32_16x16x32_bf16(a2, bp[2 * 64], acc, 0, 0, 0);
        acc = __builtin_amdgcn_mfma_f32_16x16x32_bf16(a3, bp[3 * 64], acc, 0, 0, 0);

        int col = j * 16 + cl;                 // 0..511
        unsigned short* X = (col < 256) ? xl : xr;
        int c = col & 255;
        float b = (col < 256) ? bl[c] : br[c];
#pragma unroll
        for (int q = 0; q < 4; ++q) {
            int row = rbase + q;
            if (row < n) X[(size_t)row * HC + c] = f2bf(acc[q] + b);
        }
    }
}

// ---------------- CSR build (edge_index int32: ei[0..E)=src, ei[E..2E)=dst) ----------
// hist + per-edge rank in one pass (the atomic was already paid here)
__global__ void hist_rank_kernel(const int* __restrict__ ei, int* __restrict__ cnt,
                                 int* __restrict__ rank, int E, int n)
{
    int total = E + n;
    for (int e = blockIdx.x * blockDim.x + threadIdx.x; e < total;
         e += gridDim.x * blockDim.x) {
        int dst = (e < E) ? ei[(size_t)E + e] : (e - E);
        rank[e] = atomicAdd(&cnt[dst], 1);
    }
}

// -------- hierarchical scan: 256 blocks x 256 threads, ept elements/thread --------
#define SCAN_BLOCKS 256

__global__ __launch_bounds__(256) void scan_phaseA(const int* __restrict__ cnt,
                                                   int* __restrict__ blocksums,
                                                   int n, int ept)
{
    __shared__ int red[256];
    int t = threadIdx.x;
    int g = blockIdx.x * 256 + t;
    int beg = g * ept, end = min(beg + ept, n);
    int s = 0;
    for (int i = beg; i < end; ++i) s += cnt[i];
    red[t] = s;
    __syncthreads();
    for (int d = 128; d > 0; d >>= 1) {
        if (t < d) red[t] += red[t + d];
        __syncthreads();
    }
    if (t == 0) blocksums[blockIdx.x] = red[0];
}

__global__ __launch_bounds__(256) void scan_phaseB(const int* __restrict__ blocksums,
                                                   int* __restrict__ blockoffs,
                                                   int* __restrict__ off, int n)
{
    __shared__ int sums[256];
    int t = threadIdx.x;
    sums[t] = blocksums[t];
    __syncthreads();
    for (int d = 1; d < 256; d <<= 1) {
        int v = (t >= d) ? sums[t - d] : 0;
        __syncthreads();
        sums[t] += v;
        __syncthreads();
    }
    blockoffs[t] = (t == 0) ? 0 : sums[t - 1];
    if (t == 255) off[n] = sums[255];
}

__global__ __launch_bounds__(256) void scan_phaseC(const int* __restrict__ cnt,
                                                   const int* __restrict__ blockoffs,
                                                   int* __restrict__ off,
                                                   int n, int ept)
{
    __shared__ int sums[256];
    int t = threadIdx.x;
    int g = blockIdx.x * 256 + t;
    int beg = g * ept, end = min(beg + ept, n);
    int s = 0;
    for (int i = beg; i < end; ++i) s += cnt[i];
    sums[t] = s;
    __syncthreads();
    for (int d = 1; d < 256; d <<= 1) {
        int v = (t >= d) ? sums[t - d] : 0;
        __syncthreads();
        sums[t] += v;
        __syncthreads();
    }
    int run = blockoffs[blockIdx.x] + ((t == 0) ? 0 : sums[t - 1]);
    for (int i = beg; i < end; ++i) {
        int c = cnt[i];
        off[i] = run;
        run += c;
    }
}

// atomic-free fill: pos = off[dst] + rank[e]; plain stores coalesce in L2/L3
__global__ void fill_kernel(const int* __restrict__ ei, const int* __restrict__ rank,
                            const int* __restrict__ off, int* __restrict__ csr_boff,
                            int E, int n)
{
    int total = E + n;
    for (int e = blockIdx.x * blockDim.x + threadIdx.x; e < total;
         e += gridDim.x * blockDim.x) {
        int src, dst;
        if (e < E) { src = ei[e]; dst = ei[(size_t)E + e]; }
        else       { src = dst = e - E; }
        int pos = off[dst] + rank[e];
        csr_boff[pos] = src << 9;          // src * 512 bytes (bf16 row)
    }
}

// ---------------- per-node wave aggregation (online softmax, bf16 xl/xr) -----------
__global__ __launch_bounds__(256) void gat_agg(
    const unsigned short* __restrict__ xl, const unsigned short* __restrict__ xr,
    const int* __restrict__ csr_boff, const int* __restrict__ off,
    const float* __restrict__ att, const float* __restrict__ bias,
    float* __restrict__ out, int n)
{
    int d = (blockIdx.x * blockDim.x + threadIdx.x) >> 6;   // one wave per node
    int lane = threadIdx.x & 63;
    if (d >= n) return;

    const char* xlc = (const char*)xl;
    int lo8 = lane << 3;                                    // 8B per lane
    ushort4 xru = ((const ushort4*)xr)[(size_t)d * 64 + lane];
    float xr0 = bf2f(xru.x), xr1 = bf2f(xru.y), xr2 = bf2f(xru.z), xr3 = bf2f(xru.w);
    float4 att4 = *(const float4*)(att + 4 * lane);
    att4.x *= LOG2E; att4.y *= LOG2E; att4.z *= LOG2E; att4.w *= LOG2E;

    int beg = __builtin_amdgcn_readfirstlane(off[d]);
    int end = __builtin_amdgcn_readfirstlane(off[d + 1]);
    float m = -INFINITY;      // log2 domain
    float lsum = 0.f;
    float ax = 0.f, ay = 0.f, az = 0.f, aw = 0.f;

    int i = beg;
    for (; i + 3 < end; i += 4) {
        // wave-uniform row byte-offsets -> SGPR, gathers become saddr+voffset
        int b0 = __builtin_amdgcn_readfirstlane(csr_boff[i]);
        int b1 = __builtin_amdgcn_readfirstlane(csr_boff[i + 1]);
        int b2 = __builtin_amdgcn_readfirstlane(csr_boff[i + 2]);
        int b3 = __builtin_amdgcn_readfirstlane(csr_boff[i + 3]);
        ushort4 u0 = *(const ushort4*)(xlc + b0 + lo8);
        ushort4 u1 = *(const ushort4*)(xlc + b1 + lo8);
        ushort4 u2 = *(const ushort4*)(xlc + b2 + lo8);
        ushort4 u3 = *(const ushort4*)(xlc + b3 + lo8);
        float f0[4], f1[4], f2[4], f3[4];
        unpk(u0, f0); unpk(u1, f1); unpk(u2, f2); unpk(u3, f3);

        float p0 = esc(f0, xr0, xr1, xr2, xr3, att4);
        float p1 = esc(f1, xr0, xr1, xr2, xr3, att4);
        float p2 = esc(f2, xr0, xr1, xr2, xr3, att4);
        float p3 = esc(f3, xr0, xr1, xr2, xr3, att4);

        p0 = dppadd<0xB1>(p0);  p1 = dppadd<0xB1>(p1);  p2 = dppadd<0xB1>(p2);  p3 = dppadd<0xB1>(p3);
        p0 = dppadd<0x4E>(p0);  p1 = dppadd<0x4E>(p1);  p2 = dppadd<0x4E>(p2);  p3 = dppadd<0x4E>(p3);
        p0 = dppadd<0x124>(p0); p1 = dppadd<0x124>(p1); p2 = dppadd<0x124>(p2); p3 = dppadd<0x124>(p3);
        p0 = dppadd<0x128>(p0); p1 = dppadd<0x128>(p1); p2 = dppadd<0x128>(p2); p3 = dppadd<0x128>(p3);

        float mx = fmaxf(fmaxf(p0, p1), fmaxf(p2, p3));
        if (mx > m) {
            float sc = EXP2F(m - mx);      // exp2(-inf)=0 on first group
            ax *= sc; ay *= sc; az *= sc; aw *= sc; lsum *= sc;
            m = mx;
        }
        float e0 = EXP2F(p0 - m), e1 = EXP2F(p1 - m);
        float e2 = EXP2F(p2 - m), e3 = EXP2F(p3 - m);
        ax = fmaf(e0, f0[0], fmaf(e1, f1[0], fmaf(e2, f2[0], fmaf(e3, f3[0], ax))));
        ay = fmaf(e0, f0[1], fmaf(e1, f1[1], fmaf(e2, f2[1], fmaf(e3, f3[1], ay))));
        az = fmaf(e0, f0[2], fmaf(e1, f1[2], fmaf(e2, f2[2], fmaf(e3, f3[2], az))));
        aw = fmaf(e0, f0[3], fmaf(e1, f1[3], fmaf(e2, f2[3], fmaf(e3, f3[3], aw))));
        lsum += (e0 + e1) + (e2 + e3);
    }
    for (; i < end; ++i) {                 // tail (0..3 edges)
        int b0 = __builtin_amdgcn_readfirstlane(csr_boff[i]);
        ushort4 u0 = *(const ushort4*)(xlc + b0 + lo8);
        float f0[4];
        unpk(u0, f0);
        float p0 = esc(f0, xr0, xr1, xr2, xr3, att4);
        p0 = red16(p0);
        if (p0 > m) {
            float sc = EXP2F(m - p0);
            ax *= sc; ay *= sc; az *= sc; aw *= sc; lsum *= sc;
            m = p0;
        }
        float e0 = EXP2F(p0 - m);
        ax = fmaf(e0, f0[0], ax); ay = fmaf(e0, f0[1], ay);
        az = fmaf(e0, f0[2], az); aw = fmaf(e0, f0[3], aw);
        lsum += e0;
    }

    float inv = 1.f / (lsum + 1e-16f);
    float4 b4 = *(const float4*)(bias + 4 * lane);
    float4 o;
    o.x = fmaf(ax, inv, b4.x); o.y = fmaf(ay, inv, b4.y);
    o.z = fmaf(az, inv, b4.z); o.w = fmaf(aw, inv, b4.w);
    *(float4*)(out + (size_t)d * HC + 4 * lane) = o;
}

// ---------------- BatchNorm ----------------
#define NB_BN 1024
__global__ __launch_bounds__(256) void bn_partial(const float* __restrict__ out,
                                                  float* __restrict__ partials, int n)
{
    int c = threadIdx.x;
    int b = blockIdx.x;
    int chunk = (n + NB_BN - 1) / NB_BN;
    int beg = b * chunk;
    int end = min(beg + chunk, n);
    float s = 0.f, s2 = 0.f;
    for (int r = beg; r < end; ++r) {
        float v = out[(size_t)r * HC + c];
        s += v; s2 += v * v;
    }
    partials[(size_t)b * 512 + c] = s;
    partials[(size_t)b * 512 + 256 + c] = s2;
}

// one block per channel: 256 threads sum NB_BN partials -> LDS tree -> stats
__global__ __launch_bounds__(256) void bn_final(const float* __restrict__ partials,
                                                float* __restrict__ stats, int n)
{
    int c = blockIdx.x;           // 0..255
    int t = threadIdx.x;
    float s = 0.f, s2 = 0.f;
    for (int b = t; b < NB_BN; b += 256) {
        s  += partials[(size_t)b * 512 + c];
        s2 += partials[(size_t)b * 512 + 256 + c];
    }
    __shared__ float rs[256], rs2[256];
    rs[t] = s; rs2[t] = s2;
    __syncthreads();
    for (int d = 128; d > 0; d >>= 1) {
        if (t < d) { rs[t] += rs[t + d]; rs2[t] += rs2[t + d]; }
        __syncthreads();
    }
    if (t == 0) {
        float mean = rs[0] / (float)n;
        float var = rs2[0] / (float)n - mean * mean;
        stats[c] = mean;
        stats[256 + c] = rsqrtf(var + BN_EPS);
    }
}

__global__ void bn_apply(float* __restrict__ out, const float* __restrict__ stats,
                         const float* __restrict__ gamma, const float* __restrict__ beta,
                         long long total4)
{
    long long stride = (long long)gridDim.x * blockDim.x;
    for (long long i = blockIdx.x * (long long)blockDim.x + threadIdx.x; i < total4;
         i += stride) {
        int cb = ((int)(i & 63)) * 4;
        float4 v = ((const float4*)out)[i];
        float4 o;
        o.x = fmaxf(0.f, (v.x - stats[cb + 0]) * stats[256 + cb + 0] * gamma[cb + 0] + beta[cb + 0]);
        o.y = fmaxf(0.f, (v.y - stats[cb + 1]) * stats[256 + cb + 1] * gamma[cb + 1] + beta[cb + 1]);
        o.z = fmaxf(0.f, (v.z - stats[cb + 2]) * stats[256 + cb + 2] * gamma[cb + 2] + beta[cb + 2]);
        o.w = fmaxf(0.f, (v.w - stats[cb + 3]) * stats[256 + cb + 3] * gamma[cb + 3] + beta[cb + 3]);
        ((float4*)out)[i] = o;
    }
}

// ---------------- launch ----------------
extern "C" void kernel_launch(void* const* d_in, const int* in_sizes, int n_in,
                              void* d_out, int out_size, void* d_ws, size_t ws_size,
                              hipStream_t stream)
{
    const float* feature = (const float*)d_in[0];
    const int* ei        = (const int*)d_in[1];
    const float* Wl   = (const float*)d_in[2];
    const float* bl   = (const float*)d_in[3];
    const float* Wr   = (const float*)d_in[4];
    const float* br   = (const float*)d_in[5];
    const float* att  = (const float*)d_in[6];
    const float* bias = (const float*)d_in[7];
    const float* gamma = (const float*)d_in[8];
    const float* beta  = (const float*)d_in[9];

    const int n = in_sizes[0] / IN_DIM;
    const int E = in_sizes[1] / 2;
    const int Etot = E + n;
    const int ntiles = (n + 15) / 16;

    char* ws = (char*)d_ws;
    size_t o = 0;
    auto carve = [&](size_t bytes) -> void* {
        void* p = ws + o; o = (o + bytes + 15) & ~(size_t)15; return p;
    };
    unsigned short* xl    = (unsigned short*)carve((size_t)n * HC * sizeof(short));
    unsigned short* xr    = (unsigned short*)carve((size_t)n * HC * sizeof(short));
    unsigned short* Afrag = (unsigned short*)carve((size_t)ntiles * 4 * 64 * 8 * sizeof(short));
    unsigned short* Wfrag = (unsigned short*)carve((size_t)32 * 4 * 64 * 8 * sizeof(short));
    int*   csr_boff = (int*)carve((size_t)Etot * sizeof(int));
    int*   rank    = (int*)carve((size_t)Etot * sizeof(int));
    int*   cnt     = (int*)carve((size_t)n * sizeof(int));
    int*   off     = (int*)carve((size_t)(n + 1) * sizeof(int));
    int*   blocksums = (int*)carve(SCAN_BLOCKS * sizeof(int));
    int*   blockoffs = (int*)carve(SCAN_BLOCKS * sizeof(int));
    float* partials = (float*)carve((size_t)NB_BN * 512 * sizeof(float));
    float* stats   = (float*)carve(512 * sizeof(float));
    float* outf = (float*)d_out;

    if (o > ws_size) return;

    // 1. fragment casts + MFMA projections
    cast_w<<<128, 64, 0, stream>>>(Wl, Wr, Wfrag);
    cast_a<<<ntiles, 256, 0, stream>>>(feature, Afrag, n);
    gemm_mfma<<<(ntiles + 3) / 4, 256, 0, stream>>>(Afrag, Wfrag, bl, br, xl, xr, n, ntiles);

    // 2. CSR by dst (single atomic pass with rank capture, then atomic-free fill)
    (void)hipMemsetAsync(cnt, 0, (size_t)n * sizeof(int), stream);
    hist_rank_kernel<<<2048, 256, 0, stream>>>(ei, cnt, rank, E, n);
    int ept = (n + SCAN_BLOCKS * 256 - 1) / (SCAN_BLOCKS * 256);
    scan_phaseA<<<SCAN_BLOCKS, 256, 0, stream>>>(cnt, blocksums, n, ept);
    scan_phaseB<<<1, 256, 0, stream>>>(blocksums, blockoffs, off, n);
    scan_phaseC<<<SCAN_BLOCKS, 256, 0, stream>>>(cnt, blockoffs, off, n, ept);
    fill_kernel<<<2048, 256, 0, stream>>>(ei, rank, off, csr_boff, E, n);

    // 3. per-node online-softmax aggregation
    int agg_blocks = (n + 3) / 4;
    gat_agg<<<agg_blocks, 256, 0, stream>>>(xl, xr, csr_boff, off, att, bias, outf, n);

    // 4. BatchNorm + ReLU
    bn_partial<<<NB_BN, 256, 0, stream>>>(outf, partials, n);
    bn_final<<<256, 256, 0, stream>>>(partials, stats, n);
    long long total4 = (long long)n * (HC / 4);
    bn_apply<<<4096, 256, 0, stream>>>(outf, stats, gamma, beta, total4);
}